// Round 13
// baseline (195.847 us; speedup 1.0000x reference)
//
#include <hip/hip_runtime.h>
#include <math.h>

#define NTOT 4608          // N_IN * DIM * DIM
#define NCH  144           // chunks
#define NPC  32            // n per chunk
#define NPW  8             // n per wave (4 waves/block)

typedef _Float16 f16;
typedef _Float16 f16x4 __attribute__((ext_vector_type(4)));
typedef _Float16 f16x8 __attribute__((ext_vector_type(8)));
typedef float f32x4 __attribute__((ext_vector_type(4)));

// ---- prep: blockIdx < 2304 -> wt[n][j*16+o][d] f16 (LDS-staged transpose of W)
//            blockIdx >= 2304 -> ut[b][n][d] f16 <- x[b][d][n]
__global__ __launch_bounds__(320) void prep(const float* __restrict__ x, const float* __restrict__ W,
                                            f16* __restrict__ ut, f16* __restrict__ wt) {
    __shared__ float l[2560];
    const int k = threadIdx.x;           // 0..319
    if (blockIdx.x < 2304) {
        const int n0 = blockIdx.x * 2;
        #pragma unroll
        for (int r = 0; r < 8; ++r) {
            const int f = k + r * 320;
            const int p = f / 20, q = f - p * 20;
            l[f] = W[(size_t)p * 46080 + n0 * 10 + q];
        }
        __syncthreads();
        const int half = k / 160, rr = k - half * 160;    // rr = j*16 + o
        const int j = rr >> 4, o = rr & 15;
        f16x8 v;
        #pragma unroll
        for (int d = 0; d < 8; ++d)
            v[d] = (f16)l[d * 320 + o * 20 + half * 10 + j];
        *reinterpret_cast<f16x8*>(wt + ((size_t)(n0 + half) * 160 + rr) * 8) = v;
    } else {
        const int t = (blockIdx.x - 2304) * 320 + k;      // b*4608 + n
        if (t < 128 * NTOT) {
            const int b = t / NTOT, n = t - b * NTOT;
            f16x8 v;
            #pragma unroll
            for (int d = 0; d < 8; ++d)
                v[d] = (f16)x[((size_t)b * 8 + d) * NTOT + n];
            *reinterpret_cast<f16x8*>(ut + (size_t)t * 8) = v;
        }
    }
}

// ---- kernelA: materialize u_hat (f16, layout [n][sg=0..19][b][8 halves]) + iter-0 partials.
// r7 form (parallel [4][16][164] epilogue; write-bound so 41KB LDS is fine).
__global__ __launch_bounds__(256) void kernelA(const f16* __restrict__ ut, const f16* __restrict__ wt,
                                               f16* __restrict__ uh, float* __restrict__ partial) {
    __shared__ float s0t[4][16][164];
    const int tid = threadIdx.x, w = tid >> 6, lane = tid & 63;
    const int col = lane & 15, qA = lane >> 4;
    const int chunk = blockIdx.x, bg = blockIdx.y, b0 = bg * 16;
    const int b = b0 + col;
    const int nstart = chunk * NPC + w * NPW;

    const f16* ab = wt + ((size_t)nstart * 160 + col) * 8;
    const f16* ub = ut + ((size_t)b * NTOT + nstart) * 8;
    f16* uhw = uh + (size_t)nstart * 20480 + (size_t)(qA >> 1) * 1024 + b * 8 + (qA & 1) * 4;

    const f32x4 cz = {0.f, 0.f, 0.f, 0.f};
    f32x4 s0a[10];
    #pragma unroll
    for (int m = 0; m < 10; ++m) s0a[m] = cz;

    for (int nl = 0; nl < NPW; ++nl) {
        const f16x8 bf = *reinterpret_cast<const f16x8*>(ub + nl * 8);
        #pragma unroll
        for (int m = 0; m < 10; ++m) {
            const f16x8 af = *reinterpret_cast<const f16x8*>(ab + ((size_t)nl * 160 + m * 16) * 8);
            f32x4 C = __builtin_amdgcn_mfma_f32_16x16x32_f16(af, bf, cz, 0, 0, 0);
            s0a[m] += C;
            f16x4 hv;
            hv[0] = (f16)(0.25f * C[0]); hv[1] = (f16)(0.25f * C[1]);
            hv[2] = (f16)(0.25f * C[2]); hv[3] = (f16)(0.25f * C[3]);
            *reinterpret_cast<f16x4*>(uhw + (size_t)nl * 20480 + m * 2048) = hv;
        }
    }

    #pragma unroll
    for (int m = 0; m < 10; ++m)
        *reinterpret_cast<f32x4*>(&s0t[w][col][m * 16 + qA * 4]) = s0a[m];
    __syncthreads();
    for (int r = tid; r < 2560; r += 256) {
        const int row = r / 160, slot = r - row * 160;
        float v = s0t[0][row][slot] + s0t[1][row][slot] + s0t[2][row][slot] + s0t[3][row][slot];
        partial[((size_t)chunk * 128 + b0 + row) * 160 + slot] = v;
    }
}

// ---- kernelB: one routing iteration. Wave = 8 b x 8 slot-groups (20 slots/lane).
// Lane (g = lane&7 -> b, h = lane>>3): quads Q = h+8s, s=0..4; j = 2s + (h>>2),
// o-quad = h&3. Per-lane state Aq[20]+P[20]+U[10] fits registers (no reloads).
// o-reduce: shfl_xor 8,16; parity exchange: shfl_xor 32. c-index static: j=2s+par.
__device__ __forceinline__ void kernelB_impl(const f16* __restrict__ uh, const float* __restrict__ Ar,
                                             float* __restrict__ partial, int chunk) {
    __shared__ float s1t[8][164];
    const int tid = threadIdx.x, w = tid >> 6, lane = tid & 63;
    const int g = lane & 7, h = lane >> 3;
    const int bg = blockIdx.y;               // 0..15
    const int b = bg * 8 + g;
    const int nstart = chunk * NPC + w * NPW;

    float Aq[5][4];
    #pragma unroll
    for (int s = 0; s < 5; ++s) {
        f32x4 a = *reinterpret_cast<const f32x4*>(Ar + (size_t)b * 160 + (h + 8 * s) * 4);
        #pragma unroll
        for (int i = 0; i < 4; ++i) Aq[s][i] = a[i];
    }

    float P[5][4];
    #pragma unroll
    for (int s = 0; s < 5; ++s)
        #pragma unroll
        for (int i = 0; i < 4; ++i) P[s][i] = 0.f;

    // halves: n*20480 + sg*1024 + b*8 + (h&1)*4, sg = 4s + (h>>1)
    const f16* ub = uh + (size_t)nstart * 20480 + (size_t)(h >> 1) * 1024 + b * 8 + (h & 1) * 4;

    for (int nl = 0; nl < NPW; ++nl) {
        f16x4 U[5];
        #pragma unroll
        for (int s = 0; s < 5; ++s)
            U[s] = *reinterpret_cast<const f16x4*>(ub + (size_t)nl * 20480 + s * 4096);

        float Lp[5];
        #pragma unroll
        for (int s = 0; s < 5; ++s) {
            float acc = Aq[s][0] * (float)U[s][0];
            acc = fmaf(Aq[s][1], (float)U[s][1], acc);
            acc = fmaf(Aq[s][2], (float)U[s][2], acc);
            Lp[s] = fmaf(Aq[s][3], (float)U[s][3], acc);
        }
        #pragma unroll
        for (int s = 0; s < 5; ++s) Lp[s] += __shfl_xor(Lp[s], 8, 64);
        #pragma unroll
        for (int s = 0; s < 5; ++s) Lp[s] += __shfl_xor(Lp[s], 16, 64);
        float Lo[5];
        #pragma unroll
        for (int s = 0; s < 5; ++s) Lo[s] = __shfl_xor(Lp[s], 32, 64);

        float mx = fmaxf(fmaxf(fmaxf(fmaxf(Lp[0], Lp[1]), fmaxf(Lp[2], Lp[3])), Lp[4]),
                         fmaxf(fmaxf(fmaxf(Lo[0], Lo[1]), fmaxf(Lo[2], Lo[3])), Lo[4]));
        float cown[5], sum = 0.f;
        #pragma unroll
        for (int s = 0; s < 5; ++s) { cown[s] = __expf(Lp[s] - mx); sum += cown[s]; }
        #pragma unroll
        for (int s = 0; s < 5; ++s) sum += __expf(Lo[s] - mx);
        const float inv = 1.0f / sum;

        #pragma unroll
        for (int s = 0; s < 5; ++s) {
            const float cm = cown[s] * inv;
            #pragma unroll
            for (int i = 0; i < 4; ++i)
                P[s][i] = fmaf(cm, (float)U[s][i], P[s][i]);
        }
    }

    // ordered cross-wave accumulate (4 waves = 4 n-subsets), 5.2 KB LDS
    for (int ww = 0; ww < 4; ++ww) {
        if (w == ww) {
            #pragma unroll
            for (int s = 0; s < 5; ++s) {
                const int S = (h + 8 * s) * 4;
                f32x4 p = {P[s][0], P[s][1], P[s][2], P[s][3]};
                if (ww != 0) {
                    f32x4 old = *reinterpret_cast<f32x4*>(&s1t[g][S]);
                    p += old;
                }
                *reinterpret_cast<f32x4*>(&s1t[g][S]) = p;
            }
        }
        __syncthreads();
    }
    for (int r = tid; r < 1280; r += 256) {
        const int row = r / 160, slot = r - row * 160;
        partial[((size_t)chunk * 128 + bg * 8 + row) * 160 + slot] = s1t[row][slot];
    }
}

// DESC=true walks chunks high->low (L3 tail reuse right after kernelA); B2 ascending.
template<bool DESC>
__global__ __launch_bounds__(256, 4) void kernelB(const f16* __restrict__ uh,
                                                  const float* __restrict__ Ar,
                                                  float* __restrict__ partial) {
    const int chunk = DESC ? (NCH - 1 - (int)blockIdx.x) : (int)blockIdx.x;
    kernelB_impl(uh, Ar, partial, chunk);
}

// ---- reduce_squash: sum 144 chunk-partials, squash, update A-state / write out.
// grid (128 b, 2 j-halves) x 320 threads; k2 = j'*16+o, r = chunk-stripe 0..3.
template<int MODE>   // 0: Ar = s   1: Ar += s   2: out = s
__global__ __launch_bounds__(320) void reduce_squash(const float* __restrict__ partial,
                                                     float* __restrict__ Ar, float* __restrict__ out,
                                                     float sumscale) {
    const int b = blockIdx.x, jh = blockIdx.y;
    const int k2 = threadIdx.x % 80;
    const int r  = threadIdx.x / 80;     // 0..3
    const int jp = k2 >> 4, o = k2 & 15;
    const int j  = jh * 5 + jp;
    const int slot = j * 16 + o;
    __shared__ float red[4][80];
    __shared__ float srs[80];
    float acc = 0.f;
    for (int c = r; c < NCH; c += 4)
        acc += partial[((size_t)c * 128 + b) * 160 + slot];
    red[r][k2] = acc;
    __syncthreads();
    if (r == 0) srs[k2] = (red[0][k2] + red[1][k2] + red[2][k2] + red[3][k2]) * sumscale;
    __syncthreads();
    if (r == 0) {
        float ssq = 0.f;
        #pragma unroll
        for (int oo = 0; oo < 16; ++oo) { float v = srs[jp * 16 + oo]; ssq = fmaf(v, v, ssq); }
        const float s = srs[k2] * ssq / ((1.f + ssq) * sqrtf(ssq));
        if (MODE == 0)      Ar[(size_t)b * 160 + slot] = s;
        else if (MODE == 1) Ar[(size_t)b * 160 + slot] += s;
        else                out[(size_t)b * 160 + o * 10 + j] = s;
    }
}

extern "C" void kernel_launch(void* const* d_in, const int* in_sizes, int n_in,
                              void* d_out, int out_size, void* d_ws, size_t ws_size,
                              hipStream_t stream) {
    const float* x = (const float*)d_in[0];   // (128, 8, 32, 12, 12)
    const float* W = (const float*)d_in[1];   // (8, 16, 4608, 10)
    float* out = (float*)d_out;               // (128, 16, 10)

    f16* ut = (f16*)d_ws;                                   // 128*4608*8 h     = 9.4 MB
    f16* wt = ut + (size_t)128 * NTOT * 8;                  // 4608*160*8 h     = 11.8 MB
    f16* uh = wt + (size_t)NTOT * 160 * 8;                  // 4608*20*128*8 h  = 188.7 MB
    float* Ar = (float*)(uh + (size_t)NTOT * 20 * 128 * 8); // 128*160 f32
    float* partial = Ar + 128 * 160;                        // 144*128*160 f32  = 11.8 MB

    prep<<<2304 + 1844, 320, 0, stream>>>(x, W, ut, wt);

    dim3 gA(NCH, 8), gB(NCH, 16), gRS(128, 2);
    kernelA<<<gA, 256, 0, stream>>>(ut, wt, uh, partial);
    reduce_squash<0><<<gRS, 320, 0, stream>>>(partial, Ar, out, 0.025f);  // 0.1 (c0) * 0.25 (K-dup)

    kernelB<true ><<<gB, 256, 0, stream>>>(uh, Ar, partial);
    reduce_squash<1><<<gRS, 320, 0, stream>>>(partial, Ar, out, 1.0f);

    kernelB<false><<<gB, 256, 0, stream>>>(uh, Ar, partial);
    reduce_squash<2><<<gRS, 320, 0, stream>>>(partial, Ar, out, 1.0f);
}

// Round 14
// 167.876 us; speedup vs baseline: 1.1666x; 1.1666x over previous
//
#include <hip/hip_runtime.h>
#include <math.h>

#define NTOT 4608          // N_IN * DIM * DIM
#define NCH  288           // chunks of TN n
#define TN   16            // n per chunk / per block

typedef _Float16 f16;
typedef _Float16 f16x8 __attribute__((ext_vector_type(8)));
typedef float f32x4 __attribute__((ext_vector_type(4)));

// ---- prep: blockIdx < 2304 -> wt[n][j*16+o][d] f16 (LDS-staged transpose of W)
//            blockIdx >= 2304 -> ut[b][n][d] f16 <- x[b][d][n]
__global__ __launch_bounds__(320) void prep(const float* __restrict__ x, const float* __restrict__ W,
                                            f16* __restrict__ ut, f16* __restrict__ wt) {
    __shared__ float l[2560];
    const int k = threadIdx.x;           // 0..319
    if (blockIdx.x < 2304) {
        const int n0 = blockIdx.x * 2;
        #pragma unroll
        for (int r = 0; r < 8; ++r) {
            const int f = k + r * 320;
            const int p = f / 20, q = f - p * 20;
            l[f] = W[(size_t)p * 46080 + n0 * 10 + q];
        }
        __syncthreads();
        const int half = k / 160, rr = k - half * 160;    // rr = j*16 + o
        const int j = rr >> 4, o = rr & 15;
        f16x8 v;
        #pragma unroll
        for (int d = 0; d < 8; ++d)
            v[d] = (f16)l[d * 320 + o * 20 + half * 10 + j];
        *reinterpret_cast<f16x8*>(wt + ((size_t)(n0 + half) * 160 + rr) * 8) = v;
    } else {
        const int t = (blockIdx.x - 2304) * 320 + k;      // b*4608 + n
        if (t < 128 * NTOT) {
            const int b = t / NTOT, n = t - b * NTOT;
            f16x8 v;
            #pragma unroll
            for (int d = 0; d < 8; ++d)
                v[d] = (f16)x[((size_t)b * 8 + d) * NTOT + n];
            *reinterpret_cast<f16x8*>(ut + (size_t)t * 8) = v;
        }
    }
}

// ---- routing0: iter-0 partial s (c uniform) via pure MFMA accumulation.
// grid (288, 2), 256 thr. Block stages wt tile for its 16 n (40 KB LDS, shared by
// 4 waves = 64 b). Wave: 16 b (cols), per n: 10 K-dup MFMAs chained into P[m].
// P = Sum_n 4*uh; RS applies 0.025 (= 0.1 * 0.25).
__global__ __launch_bounds__(256) void routing0(const f16* __restrict__ ut, const f16* __restrict__ wt,
                                                float* __restrict__ partial) {
    __shared__ f16x8 lwt[TN * 160];
    const int tid = threadIdx.x, w = tid >> 6, lane = tid & 63;
    const int col = lane & 15, qA = lane >> 4;
    const int chunk = blockIdx.x;
    const int b = (blockIdx.y * 4 + w) * 16 + col;

    const f16x8* gsrc = reinterpret_cast<const f16x8*>(wt + (size_t)chunk * TN * 160 * 8);
    #pragma unroll
    for (int r = 0; r < 10; ++r) lwt[tid + r * 256] = gsrc[tid + r * 256];
    __syncthreads();

    const f16* ubp = ut + ((size_t)b * NTOT + chunk * TN) * 8;
    const f32x4 cz = {0.f, 0.f, 0.f, 0.f};
    f32x4 P[10];
    #pragma unroll
    for (int m = 0; m < 10; ++m) P[m] = cz;

    f16x8 bf = *reinterpret_cast<const f16x8*>(ubp);
    #pragma unroll 1
    for (int nl = 0; nl < TN; ++nl) {
        f16x8 bfn;
        if (nl < TN - 1) bfn = *reinterpret_cast<const f16x8*>(ubp + (nl + 1) * 8);
        #pragma unroll
        for (int m = 0; m < 10; ++m)
            P[m] = __builtin_amdgcn_mfma_f32_16x16x32_f16(lwt[nl * 160 + m * 16 + col], bf, P[m], 0, 0, 0);
        bf = bfn;
    }

    float* pp = partial + ((size_t)chunk * 128 + b) * 160 + qA * 4;
    #pragma unroll
    for (int m = 0; m < 10; ++m)
        *reinterpret_cast<f32x4*>(pp + m * 16) = P[m];
}

// ---- routing_sm: one softmax routing iteration, uh recomputed via MFMA.
// Ar holds 0.25*A so t[m] = dot(Ar4, C=4uh) = A.uh. Softmax without max-subtract
// (logits bounded |t| < ~25; validated r10/r11). P[m] += c*C (carries 4x; RS *0.25).
__global__ __launch_bounds__(256) void routing_sm(const f16* __restrict__ ut, const f16* __restrict__ wt,
                                                  const float* __restrict__ Ar,
                                                  float* __restrict__ partial) {
    __shared__ f16x8 lwt[TN * 160];
    const int tid = threadIdx.x, w = tid >> 6, lane = tid & 63;
    const int col = lane & 15, qA = lane >> 4;
    const int chunk = blockIdx.x;
    const int b = (blockIdx.y * 4 + w) * 16 + col;

    const f16x8* gsrc = reinterpret_cast<const f16x8*>(wt + (size_t)chunk * TN * 160 * 8);
    #pragma unroll
    for (int r = 0; r < 10; ++r) lwt[tid + r * 256] = gsrc[tid + r * 256];
    __syncthreads();

    float A4[10][4];
    #pragma unroll
    for (int m = 0; m < 10; ++m) {
        f32x4 a = *reinterpret_cast<const f32x4*>(Ar + (size_t)b * 160 + m * 16 + qA * 4);
        #pragma unroll
        for (int i = 0; i < 4; ++i) A4[m][i] = a[i];
    }

    const f16* ubp = ut + ((size_t)b * NTOT + chunk * TN) * 8;
    const f32x4 cz = {0.f, 0.f, 0.f, 0.f};
    f32x4 P[10];
    #pragma unroll
    for (int m = 0; m < 10; ++m) P[m] = cz;

    f16x8 bf = *reinterpret_cast<const f16x8*>(ubp);
    #pragma unroll 1
    for (int nl = 0; nl < TN; ++nl) {
        f16x8 bfn;
        if (nl < TN - 1) bfn = *reinterpret_cast<const f16x8*>(ubp + (nl + 1) * 8);

        f32x4 C[10];
        #pragma unroll
        for (int m = 0; m < 10; ++m)
            C[m] = __builtin_amdgcn_mfma_f32_16x16x32_f16(lwt[nl * 160 + m * 16 + col], bf, cz, 0, 0, 0);

        float t[10];
        #pragma unroll
        for (int m = 0; m < 10; ++m) {
            float acc = A4[m][0] * C[m][0];
            acc = fmaf(A4[m][1], C[m][1], acc);
            acc = fmaf(A4[m][2], C[m][2], acc);
            t[m] = fmaf(A4[m][3], C[m][3], acc);
        }
        #pragma unroll
        for (int m = 0; m < 10; ++m) t[m] += __shfl_xor(t[m], 16, 64);
        #pragma unroll
        for (int m = 0; m < 10; ++m) t[m] += __shfl_xor(t[m], 32, 64);

        float c[10], sum = 0.f;
        #pragma unroll
        for (int m = 0; m < 10; ++m) { c[m] = __expf(t[m]); sum += c[m]; }
        const float inv = 1.0f / sum;

        #pragma unroll
        for (int m = 0; m < 10; ++m) {
            const float cm = c[m] * inv;
            #pragma unroll
            for (int i = 0; i < 4; ++i)
                P[m][i] = fmaf(cm, C[m][i], P[m][i]);
        }
        bf = bfn;
    }

    float* pp = partial + ((size_t)chunk * 128 + b) * 160 + qA * 4;
    #pragma unroll
    for (int m = 0; m < 10; ++m)
        *reinterpret_cast<f32x4*>(pp + m * 16) = P[m];
}

// ---- reduce_squash: sum 288 chunk-partials, squash, update A-state / write out.
// grid (128 b, 2 j-halves) x 320 threads; k2 = j'*16+o, r = chunk-stripe 0..3.
// Ar stores 0.25*A (K-dup folding); out gets true s.
template<int MODE>   // 0: Ar = s/4   1: Ar += s/4   2: out = s
__global__ __launch_bounds__(320) void reduce_squash(const float* __restrict__ partial,
                                                     float* __restrict__ Ar, float* __restrict__ out,
                                                     float sumscale) {
    const int b = blockIdx.x, jh = blockIdx.y;
    const int k2 = threadIdx.x % 80;
    const int r  = threadIdx.x / 80;     // 0..3
    const int jp = k2 >> 4, o = k2 & 15;
    const int j  = jh * 5 + jp;
    const int slot = j * 16 + o;
    __shared__ float red[4][80];
    __shared__ float srs[80];
    float acc = 0.f;
    for (int c = r; c < NCH; c += 4)
        acc += partial[((size_t)c * 128 + b) * 160 + slot];
    red[r][k2] = acc;
    __syncthreads();
    if (r == 0) srs[k2] = (red[0][k2] + red[1][k2] + red[2][k2] + red[3][k2]) * sumscale;
    __syncthreads();
    if (r == 0) {
        float ssq = 0.f;
        #pragma unroll
        for (int oo = 0; oo < 16; ++oo) { float v = srs[jp * 16 + oo]; ssq = fmaf(v, v, ssq); }
        const float s = srs[k2] * ssq / ((1.f + ssq) * sqrtf(ssq));
        if (MODE == 0)      Ar[(size_t)b * 160 + slot] = 0.25f * s;
        else if (MODE == 1) Ar[(size_t)b * 160 + slot] += 0.25f * s;
        else                out[(size_t)b * 160 + o * 10 + j] = s;
    }
}

extern "C" void kernel_launch(void* const* d_in, const int* in_sizes, int n_in,
                              void* d_out, int out_size, void* d_ws, size_t ws_size,
                              hipStream_t stream) {
    const float* x = (const float*)d_in[0];   // (128, 8, 32, 12, 12)
    const float* W = (const float*)d_in[1];   // (8, 16, 4608, 10)
    float* out = (float*)d_out;               // (128, 16, 10)

    f16* ut = (f16*)d_ws;                                   // 128*4608*8 h     = 9.4 MB
    f16* wt = ut + (size_t)128 * NTOT * 8;                  // 4608*160*8 h     = 11.8 MB
    float* Ar = (float*)(wt + (size_t)NTOT * 160 * 8);      // 128*160 f32
    float* partial = Ar + 128 * 160;                        // 288*128*160 f32  = 23.6 MB

    prep<<<2304 + 1844, 320, 0, stream>>>(x, W, ut, wt);

    dim3 gR(NCH, 2), gRS(128, 2);
    routing0<<<gR, 256, 0, stream>>>(ut, wt, partial);
    reduce_squash<0><<<gRS, 320, 0, stream>>>(partial, Ar, out, 0.025f);  // 0.1 (c0) * 0.25 (K-dup)

    routing_sm<<<gR, 256, 0, stream>>>(ut, wt, Ar, partial);
    reduce_squash<1><<<gRS, 320, 0, stream>>>(partial, Ar, out, 0.25f);

    routing_sm<<<gR, 256, 0, stream>>>(ut, wt, Ar, partial);
    reduce_squash<2><<<gRS, 320, 0, stream>>>(partial, Ar, out, 0.25f);
}